// Round 16
// baseline (200.755 us; speedup 1.0000x reference)
//
#include <hip/hip_runtime.h>
#include <hip/hip_bf16.h>

typedef __attribute__((ext_vector_type(8))) short s8v;   // 8 x bf16
typedef __attribute__((ext_vector_type(4))) float f32x4; // MFMA acc

__device__ __forceinline__ float sigf(float x) { return 1.0f / (1.0f + __expf(-x)); }
__device__ __forceinline__ float tanh_fast(float x) { return 1.0f - 2.0f / (1.0f + __expf(2.0f * x)); }
__device__ __forceinline__ ushort f2bf(float f) {
    union { __hip_bfloat16 b; ushort u; } v; v.b = __float2bfloat16(f); return v.u;
}

// ---------------- prepass ----------------
// PX4[ty*128+j] = {gi,gf,gg,go} partial gates for emb[ty] (fp32 dots + fused bias)
// Wcol4[j] = Wih[:,127] for the 4 gate rows of j (rank-1 node_args correction)
// HLEAF/CLEAF[ty][j]: leaf-level h(bf16)/c(fp32) for non-special types
// Bpack (h-part only, K=256): (((bn*8 + kk)*4 + seg)*128 + nl)*8 + t
//   col order nl -> g=(nl>>4)&3, j = bn*32 + (nl>>6)*16 + (nl&15)
__global__ __launch_bounds__(256) void prepass(
    const float* __restrict__ emb,
    const float* __restrict__ Wih, const float* __restrict__ Whh,
    const float* __restrict__ bih, const float* __restrict__ bhh,
    ushort* __restrict__ Bpack, float4* __restrict__ PX4, float4* __restrict__ Wcol4,
    ushort* __restrict__ HLEAF, float* __restrict__ CLEAF)
{
    const int bx = blockIdx.x;
    const int tid = threadIdx.x;
    if (bx < 64) {
        const int gid = bx * 256 + tid;     // 0..16383 -> (ty, j)
        const int ty = gid >> 7;
        const int j  = gid & 127;
        const float* e = emb + (size_t)ty * 128;
        float d[4];
        #pragma unroll
        for (int g = 0; g < 4; ++g) {
            const int row = g * 256 + j;
            const float* wr = Wih + (size_t)row * 128;
            float acc = bih[row] + bhh[row];
            #pragma unroll 8
            for (int k = 0; k < 128; k += 4) {
                float4 ev = *(const float4*)(e + k);
                float4 wv = *(const float4*)(wr + k);
                acc = fmaf(ev.x, wv.x, acc); acc = fmaf(ev.y, wv.y, acc);
                acc = fmaf(ev.z, wv.z, acc); acc = fmaf(ev.w, wv.w, acc);
            }
            d[g] = acc;
        }
        PX4[gid] = make_float4(d[0], d[1], d[2], d[3]);
        const float cn = sigf(d[0]) * tanh_fast(d[2]);
        CLEAF[gid] = cn;
        HLEAF[gid] = f2bf(sigf(d[3]) * tanh_fast(cn));
        if (ty == 0)
            Wcol4[j] = make_float4(Wih[(size_t)j * 128 + 127],
                                   Wih[(size_t)(256 + j) * 128 + 127],
                                   Wih[(size_t)(512 + j) * 128 + 127],
                                   Wih[(size_t)(768 + j) * 128 + 127]);
    } else {
        const int gid = (bx - 64) * 256 + tid;   // 0..16383 Bpack
        const int nl  = gid & 127;
        const int seg = (gid >> 7) & 3;
        const int rest = gid >> 9;        // 0..31
        const int kk = rest & 7;
        const int bn = rest >> 3;
        const int g  = (nl >> 4) & 3;
        const int j  = bn * 32 + ((nl >> 6) << 4) + (nl & 15);
        const int row = g * 256 + j;
        const int k = kk * 32 + seg * 8;
        const float* src = Whh + (size_t)row * 256 + k;
        float4 w0 = *(const float4*)(src);
        float4 w1 = *(const float4*)(src + 4);
        ushort o[8] = { f2bf(w0.x), f2bf(w0.y), f2bf(w0.z), f2bf(w0.w),
                        f2bf(w1.x), f2bf(w1.y), f2bf(w1.z), f2bf(w1.w) };
        *(s8v*)(Bpack + (size_t)gid * 8) = *(const s8v*)o;
    }
}

// ---------------- stage 2 (shared): parents M=32, N=512, K=256 from LDS children ----------------
template<bool ROOT>
__device__ __forceinline__ void stage2_parents(
    const ushort (*hC)[136], const float (*cC)[132],
    const int* __restrict__ nt, const float* __restrict__ na,
    const ushort* __restrict__ Bpack, const float4* __restrict__ PX4,
    const float4* __restrict__ Wcol4, float e1, float e2,
    ushort* __restrict__ h_out, float* __restrict__ c_out, float* hs,
    int startP, int nP, int b)
{
    const int tid  = threadIdx.x;
    const int lane = tid & 63;
    const int wave = tid >> 6;
    const int bn = wave >> 1, wn = wave & 1;
    const int lc = lane & 15, seg = lane >> 4;
    const int koff = seg * 8;

    int mcl[2];
    #pragma unroll
    for (int mi = 0; mi < 2; ++mi) {
        int m = mi * 16 + lc;
        int mPg = 32 * b + m;
        int mc = mPg < nP ? mPg : nP - 1;
        mcl[mi] = mc - 32 * b;
    }
    const ushort* pb = Bpack + (size_t)bn * 32768 + (size_t)seg * 1024
                             + (size_t)(wn * 64 + lc) * 8;

    f32x4 acc[2][4];
    #pragma unroll
    for (int mi = 0; mi < 2; ++mi)
        #pragma unroll
        for (int f = 0; f < 4; ++f) acc[mi][f] = (f32x4){0.f, 0.f, 0.f, 0.f};

    #pragma unroll
    for (int kk = 0; kk < 8; ++kk) {
        const int hi = kk >> 2, off = (kk & 3) * 32;
        s8v a0 = *(const s8v*)(&hC[2 * mcl[0] + hi][off + koff]);
        s8v a1 = *(const s8v*)(&hC[2 * mcl[1] + hi][off + koff]);
        #pragma unroll
        for (int f = 0; f < 4; ++f) {
            s8v bb = *(const s8v*)(pb + (size_t)kk * 4096 + f * 128);
            acc[0][f] = __builtin_amdgcn_mfma_f32_16x16x32_bf16(a0, bb, acc[0][f], 0, 0, 0);
            acc[1][f] = __builtin_amdgcn_mfma_f32_16x16x32_bf16(a1, bb, acc[1][f], 0, 0, 0);
        }
    }

    const int j = bn * 32 + wn * 16 + lc;
    const float4 wc = Wcol4[j];
    #pragma unroll
    for (int mi = 0; mi < 2; ++mi) {
        #pragma unroll
        for (int r = 0; r < 4; ++r) {
            const int m = mi * 16 + seg * 4 + r;
            const int mPg = 32 * b + m;
            if (mPg < nP) {
                const int node = startP + mPg;
                const int ty = nt[node];
                const float corr = (ty == 1) ? (na[node] - e1)
                                 : ((ty == 2) ? (na[node] - e2) : 0.0f);
                const float4 px = PX4[(size_t)ty * 128 + j];
                const float gi = acc[mi][0][r] + px.x + corr * wc.x;
                const float gf = acc[mi][1][r] + px.y + corr * wc.y;
                const float gg = acc[mi][2][r] + px.z + corr * wc.z;
                const float go = acc[mi][3][r] + px.w + corr * wc.w;
                const float c0 = cC[m][j];
                const float cn = sigf(gf) * c0 + sigf(gi) * tanh_fast(gg);
                const float hn = sigf(go) * tanh_fast(cn);
                if (ROOT) {
                    hs[j] = hn;   // nP==1: only m==0 lanes reach here
                } else {
                    h_out[(size_t)mPg * 128 + j] = f2bf(hn);
                    if (!(mPg & 1)) c_out[(size_t)(mPg >> 1) * 128 + j] = cn;
                }
            }
        }
    }
}

// ---------------- pair (15,14): leaf children via HLEAF/CLEAF row copies + parent GEMM ----------------
__global__ __launch_bounds__(512) void pair_leaf(
    const int* __restrict__ nt, const float* __restrict__ na,
    const float* __restrict__ emb,
    const ushort* __restrict__ Bpack, const float4* __restrict__ PX4,
    const float4* __restrict__ Wcol4,
    const ushort* __restrict__ HLEAF, const float* __restrict__ CLEAF,
    ushort* __restrict__ h_out, float* __restrict__ c_out)
{
    __shared__ __align__(16) ushort hC[64][136];
    __shared__ float cC[32][132];
    const int tid = threadIdx.x;
    const int b = blockIdx.x;
    const float e1 = emb[255], e2 = emb[383];

    // stage 1: 64 leaves — coalesced row copies (special types: in-thread fixup)
    {
        const int mloc = tid >> 3;      // 0..63
        const int p8   = tid & 7;       // 16-elem chunk
        const int node = 32767 + 64 * b + mloc;
        const int ty = nt[node];
        if (ty != 1 && ty != 2) {
            *(s8v*)(&hC[mloc][p8 * 16])     = *(const s8v*)(HLEAF + (size_t)ty * 128 + p8 * 16);
            *(s8v*)(&hC[mloc][p8 * 16 + 8]) = *(const s8v*)(HLEAF + (size_t)ty * 128 + p8 * 16 + 8);
            if (!(mloc & 1)) {
                const float* cr = CLEAF + (size_t)ty * 128 + p8 * 16;
                #pragma unroll
                for (int q = 0; q < 16; ++q) cC[mloc >> 1][p8 * 16 + q] = cr[q];
            }
        } else {
            const float corr = na[node] - ((ty == 1) ? e1 : e2);
            #pragma unroll
            for (int q = 0; q < 16; ++q) {
                const int jj = p8 * 16 + q;
                const float4 px = PX4[(size_t)ty * 128 + jj];
                const float4 wc = Wcol4[jj];
                const float gi = px.x + corr * wc.x;
                const float gg = px.z + corr * wc.z;
                const float go = px.w + corr * wc.w;
                const float cn = sigf(gi) * tanh_fast(gg);
                const float hn = sigf(go) * tanh_fast(cn);
                hC[mloc][jj] = f2bf(hn);
                if (!(mloc & 1)) cC[mloc >> 1][jj] = cn;
            }
        }
    }
    __syncthreads();
    stage2_parents<false>(hC, cC, nt, na, Bpack, PX4, Wcol4, e1, e2,
                          h_out, c_out, nullptr, 16383, 16384, b);
}

// ---------------- pair (C,P) for internal levels; ROOTHEAD adds level-0 + MLP head ----------------
template<int ROOTHEAD>
__global__ __launch_bounds__(512) void pair_h(
    const int* __restrict__ nt, const float* __restrict__ na,
    const float* __restrict__ emb,
    const ushort* __restrict__ Bpack, const float4* __restrict__ PX4,
    const float4* __restrict__ Wcol4,
    const ushort* __restrict__ h_in, const float* __restrict__ c_in,
    ushort* __restrict__ h_out, float* __restrict__ c_out,
    int startC, int startP, int nP,
    const float* __restrict__ W1, const float* __restrict__ b1,
    const float* __restrict__ W2, const float* __restrict__ b2,
    const float* __restrict__ vmask, float* __restrict__ out)
{
    __shared__ __align__(16) ushort hC[64][136];
    __shared__ float cC[32][132];
    __shared__ float hs[128];
    __shared__ float as[128];

    const int tid  = threadIdx.x;
    const int lane = tid & 63;
    const int wave = tid >> 6;
    const int lc = lane & 15, seg = lane >> 4;
    const int koff = seg * 8;
    const int nC = 2 * nP;
    const int b = blockIdx.x;
    const float e1 = emb[255], e2 = emb[383];

    // ===== stage 1: children, M=64, N=512, K=256 (grandchildren h from global) =====
    {
        const int wm2 = wave >> 2;
        const int bn  = wave & 3;
        const ushort* ph[2][2];
        #pragma unroll
        for (int mi = 0; mi < 2; ++mi) {
            int mloc = wm2 * 32 + mi * 16 + lc;
            int cg = 64 * b + mloc;
            int cgc = cg < nC ? cg : nC - 1;
            ph[mi][0] = h_in + (size_t)(2 * cgc) * 128 + koff;
            ph[mi][1] = h_in + (size_t)(2 * cgc + 1) * 128 + koff;
        }
        const ushort* pb = Bpack + (size_t)bn * 32768 + (size_t)seg * 1024
                                 + (size_t)lc * 8;

        f32x4 acc[2][8];
        #pragma unroll
        for (int mi = 0; mi < 2; ++mi)
            #pragma unroll
            for (int f = 0; f < 8; ++f) acc[mi][f] = (f32x4){0.f, 0.f, 0.f, 0.f};

        #pragma unroll
        for (int kk = 0; kk < 8; ++kk) {
            const int hi = kk >> 2, off = (kk & 3) * 32;
            s8v a0 = *(const s8v*)(ph[0][hi] + off);
            s8v a1 = *(const s8v*)(ph[1][hi] + off);
            #pragma unroll
            for (int f = 0; f < 8; ++f) {
                s8v bb = *(const s8v*)(pb + (size_t)kk * 4096 + f * 128);
                acc[0][f] = __builtin_amdgcn_mfma_f32_16x16x32_bf16(a0, bb, acc[0][f], 0, 0, 0);
                acc[1][f] = __builtin_amdgcn_mfma_f32_16x16x32_bf16(a1, bb, acc[1][f], 0, 0, 0);
            }
        }
        #pragma unroll
        for (int bh = 0; bh < 2; ++bh) {
            const int j = bn * 32 + bh * 16 + lc;
            const float4 wc = Wcol4[j];
            #pragma unroll
            for (int mi = 0; mi < 2; ++mi) {
                #pragma unroll
                for (int r = 0; r < 4; ++r) {
                    const int mloc = wm2 * 32 + mi * 16 + seg * 4 + r;
                    const int cg = 64 * b + mloc;
                    if (cg < nC) {
                        const int node = startC + cg;
                        const int ty = nt[node];
                        const float corr = (ty == 1) ? (na[node] - e1)
                                         : ((ty == 2) ? (na[node] - e2) : 0.0f);
                        const float4 px = PX4[(size_t)ty * 128 + j];
                        const float gi = acc[mi][bh * 4 + 0][r] + px.x + corr * wc.x;
                        const float gf = acc[mi][bh * 4 + 1][r] + px.y + corr * wc.y;
                        const float gg = acc[mi][bh * 4 + 2][r] + px.z + corr * wc.z;
                        const float go = acc[mi][bh * 4 + 3][r] + px.w + corr * wc.w;
                        const float c0 = c_in[(size_t)cg * 128 + j];
                        const float cn = sigf(gf) * c0 + sigf(gi) * tanh_fast(gg);
                        const float hn = sigf(go) * tanh_fast(cn);
                        hC[mloc][j] = f2bf(hn);
                        if (!(mloc & 1)) cC[mloc >> 1][j] = cn;
                    }
                }
            }
        }
    }
    __syncthreads();

    // ===== stage 2: parents =====
    if (ROOTHEAD) {
        stage2_parents<true>(hC, cC, nt, na, Bpack, PX4, Wcol4, e1, e2,
                             nullptr, nullptr, hs, startP, nP, b);
        __syncthreads();
        if (tid < 128) {
            float a1h = b1[tid];
            #pragma unroll 4
            for (int k = 0; k < 128; ++k) a1h = fmaf(hs[k], W1[tid * 128 + k], a1h);
            as[tid] = fmaxf(a1h, 0.0f);
        }
        __syncthreads();
        if (tid < 32) {
            float l = b2[tid];
            #pragma unroll 4
            for (int k = 0; k < 128; ++k) l = fmaf(as[k], W2[tid * 128 + k], l);
            l = (l + logf(vmask[tid])) * (1.0f / 3.0f);
            float mx = l;
            #pragma unroll
            for (int o = 16; o >= 1; o >>= 1) mx = fmaxf(mx, __shfl_xor(mx, o, 32));
            const float e = __expf(l - mx);
            float s = e;
            #pragma unroll
            for (int o = 16; o >= 1; o >>= 1) s += __shfl_xor(s, o, 32);
            out[tid] = e / s;
        }
    } else {
        stage2_parents<false>(hC, cC, nt, na, Bpack, PX4, Wcol4, e1, e2,
                              h_out, c_out, nullptr, startP, nP, b);
    }
}

extern "C" void kernel_launch(void* const* d_in, const int* in_sizes, int n_in,
                              void* d_out, int out_size, void* d_ws, size_t ws_size,
                              hipStream_t stream)
{
    const int*   node_types = (const int*)  d_in[0];
    const float* node_args  = (const float*)d_in[1];
    const float* vmask      = (const float*)d_in[2];
    const float* emb        = (const float*)d_in[3];
    const float* Wih        = (const float*)d_in[4];
    const float* Whh        = (const float*)d_in[5];
    const float* bih        = (const float*)d_in[6];
    const float* bhh        = (const float*)d_in[7];
    const float* W1         = (const float*)d_in[8];
    const float* b1         = (const float*)d_in[9];
    const float* W2         = (const float*)d_in[10];
    const float* b2         = (const float*)d_in[11];

    char* w = (char*)d_ws;
    ushort* Bpack = (ushort*)(w);                 // 16384*8*2   =   262,144
    float4* PX4   = (float4*)(w + 262144);        // 16384*16    =   262,144
    float4* Wcol4 = (float4*)(w + 524288);        // 128*16      =     2,048
    ushort* HLEAF = (ushort*)(w + 526336);        // 16384*2     =    32,768
    float*  CLEAF = (float*) (w + 559104);        // 16384*4     =    65,536
    ushort* hA    = (ushort*)(w + 624640);        // 16384*128*2 = 4,194,304
    float*  cA    = (float*) (w + 4818944);       // 8192*128*4  = 4,194,304
    ushort* hB    = (ushort*)(w + 9013248);       // 4096*128*2  = 1,048,576
    float*  cB    = (float*) (w + 10061824);      // 2048*128*4  = 1,048,576

    float* out = (float*)d_out;

    prepass<<<128, 256, 0, stream>>>(emb, Wih, Whh, bih, bhh,
                                     Bpack, PX4, Wcol4, HLEAF, CLEAF);

    // (15,14) leaf -> A
    pair_leaf<<<512, 512, 0, stream>>>(node_types, node_args, emb,
                                       Bpack, PX4, Wcol4, HLEAF, CLEAF, hA, cA);
    // internal pairs
    pair_h<0><<<128, 512, 0, stream>>>(node_types, node_args, emb, Bpack, PX4, Wcol4,
        hA, cA, hB, cB, 8191, 4095, 4096, nullptr, nullptr, nullptr, nullptr, nullptr, nullptr);
    pair_h<0><<< 32, 512, 0, stream>>>(node_types, node_args, emb, Bpack, PX4, Wcol4,
        hB, cB, hA, cA, 2047, 1023, 1024, nullptr, nullptr, nullptr, nullptr, nullptr, nullptr);
    pair_h<0><<<  8, 512, 0, stream>>>(node_types, node_args, emb, Bpack, PX4, Wcol4,
        hA, cA, hB, cB,  511,  255,  256, nullptr, nullptr, nullptr, nullptr, nullptr, nullptr);
    pair_h<0><<<  2, 512, 0, stream>>>(node_types, node_args, emb, Bpack, PX4, Wcol4,
        hB, cB, hA, cA,  127,   63,   64, nullptr, nullptr, nullptr, nullptr, nullptr, nullptr);
    pair_h<0><<<  1, 512, 0, stream>>>(node_types, node_args, emb, Bpack, PX4, Wcol4,
        hA, cA, hB, cB,   31,   15,   16, nullptr, nullptr, nullptr, nullptr, nullptr, nullptr);
    pair_h<0><<<  1, 512, 0, stream>>>(node_types, node_args, emb, Bpack, PX4, Wcol4,
        hB, cB, hA, cA,    7,    3,    4, nullptr, nullptr, nullptr, nullptr, nullptr, nullptr);
    // (1,0) + head
    pair_h<1><<<  1, 512, 0, stream>>>(node_types, node_args, emb, Bpack, PX4, Wcol4,
        hA, cA, hB, cB,    1,    0,    1, W1, b1, W2, b2, vmask, out);
}